// Round 10
// baseline (29.695 us; speedup 1.0000x reference)
//
#include <hip/hip_runtime.h>
#include <hip/hip_bf16.h>
#include <hip/hip_fp16.h>

// Reference collapses: softmax over singleton axis==1 -> attention weights == 1,
// so ctx[b,h] = sum_l fmap[b,l,h], out[b,t,c] = dot(ctx[b,:], W_gen[c,:]) + b_gen[c]
// broadcast over all t. LSTM / embedding / text are dead code.
//
// R9 post-mortem: bank conflicts were negligible (96 cyc/wave); pk_fma asm
// regressed. R10: K2 was L2-read + VALU heavy -> f16 W (half L2 traffic),
// v_dot2_f32_f16 (half FMA instrs), c-split waves (4x fewer DPP reduces,
// no cross-wave combine). K1 additionally emits f16 W and f16 ctx.

constexpr int Hd = 512;   // hidden (K)
constexpr int Cd = 4096;  // classes (N)
constexpr int Bd = 64;    // batch (M)
constexpr int Td = 32;    // timesteps (broadcast)
constexpr int Ld = 256;   // FH*FW
constexpr int CG = 32;    // c per block in K2

// all-DPP 16-lane rotate-add; 0x121:ror1 0x122:ror2 0x124:ror4 0x128:ror8
template<int CTRL>
__device__ __forceinline__ float ror_add(float v) {
    int r = __builtin_amdgcn_update_dpp(0, __float_as_int(v), CTRL, 0xF, 0xF, false);
    return v + __int_as_float(r);
}

__device__ __forceinline__ float dot2(unsigned int a, unsigned int b, float acc) {
    asm("v_dot2_f32_f16 %0, %1, %2, %0" : "+v"(acc) : "v"(a), "v"(b));
    return acc;
}

// ---------------- K1: row-sums -> ctx_h (f16), and W -> W_h (f16) ----------------
// grid 1024 x 256thr. Wave = 8 fmap rows (R5 structure); every thread also
// converts 8 W floats (262144 thr x 8 = 2097152 = |W|).
__global__ __launch_bounds__(256) void prep(const float* __restrict__ in,
                                            const float* __restrict__ Wgen,
                                            __half* __restrict__ ctx_h,
                                            __half* __restrict__ W_h) {
    const int lane = threadIdx.x & 63;
    const int gw   = blockIdx.x * 4 + (threadIdx.x >> 6);
    const int row0 = gw * 8;
    const float4* in4 = reinterpret_cast<const float4*>(in);

    // --- W convert: 8 consecutive floats -> 8 f16 (one uint4 store) ---
    {
        const int t = blockIdx.x * 256 + threadIdx.x;
        const float4* W4 = reinterpret_cast<const float4*>(Wgen) + (size_t)t * 2;
        const float4 a = W4[0], b = W4[1];
        __half2 h[4];
        h[0] = __floats2half2_rn(a.x, a.y);
        h[1] = __floats2half2_rn(a.z, a.w);
        h[2] = __floats2half2_rn(b.x, b.y);
        h[3] = __floats2half2_rn(b.z, b.w);
        *reinterpret_cast<uint4*>(W_h + (size_t)t * 8) =
            *reinterpret_cast<const uint4*>(h);
    }

    // --- fmap row sums (R5 structure, f16 output) ---
    float4 v[8];
    #pragma unroll
    for (int r = 0; r < 8; ++r)
        v[r] = in4[(size_t)(row0 + r) * 64 + lane];

    float s[8];
    #pragma unroll
    for (int r = 0; r < 8; ++r) {
        float a = v[r].x + v[r].y + v[r].z + v[r].w;
        a += __shfl_xor(a, 16, 64);
        a += __shfl_xor(a, 32, 64);
        a = ror_add<0x121>(a);
        a = ror_add<0x122>(a);
        a = ror_add<0x124>(a);
        a = ror_add<0x128>(a);
        s[r] = a;
    }
    if (lane < 8) {
        float val = s[0];
        #pragma unroll
        for (int r = 1; r < 8; ++r) val = (lane == r) ? s[r] : val;
        ctx_h[row0 + lane] = __float2half(val);
    }
}

// ---------------- K2: out[b][t][c] = ctx[b,:]·W[c,:] + bias, bcast over t -------
// grid (Cd/CG=128, Bd/4=16) = 2048 blocks, 4 waves. Same-cx blocks stride 128
// (== 0 mod 8) -> same XCD -> W_h slice L2-resident across 16 b-replicas.
// Wave w owns c-quads {2w, 2w+1} over the FULL K=512: lane (cpart,hp) dots
// 32 f16 (16 v_dot2, fp32 acc) then one 4-step DPP reduce over 16 hp lanes.
// No cross-wave combine needed; tiny final4[] LDS only for store coalescing.
__global__ __launch_bounds__(256) void gemm_bcast(const __half* __restrict__ ctx_h,
                                                  const __half* __restrict__ W_h,
                                                  const float* __restrict__ bgen,
                                                  float* __restrict__ out) {
    __shared__ float4 final4[CG];   // [c_local] -> float4 over 4 b
    const int tid   = threadIdx.x;
    const int w     = tid >> 6;
    const int lane  = tid & 63;
    const int cpart = lane >> 4;
    const int hp    = lane & 15;
    const int cblk  = blockIdx.x * CG;
    const int b0    = blockIdx.y * 4;

    // xr[bb][i] = ctx_h[b0+bb][hp*32 + i*8 .. +7]  (4 x uint4 = 32 f16 per bb)
    uint4 xr[4][4];
    #pragma unroll
    for (int bb = 0; bb < 4; ++bb) {
        const uint4* p = reinterpret_cast<const uint4*>(
            ctx_h + (size_t)(b0 + bb) * Hd + hp * 32);
        #pragma unroll
        for (int i = 0; i < 4; ++i) xr[bb][i] = p[i];
    }

    #pragma unroll
    for (int qq = 0; qq < 2; ++qq) {
        const int q = w * 2 + qq;
        const int c = cblk + q * 4 + cpart;
        // wave reads one contiguous 4KB W chunk (4 rows x 1KB) — coalesced
        const uint4* Wr = reinterpret_cast<const uint4*>(
            W_h + (size_t)c * Hd + hp * 32);
        uint4 wr[4];
        #pragma unroll
        for (int i = 0; i < 4; ++i) wr[i] = Wr[i];

        float acc[4];
        #pragma unroll
        for (int bb = 0; bb < 4; ++bb) {
            float a = 0.f;
            #pragma unroll
            for (int i = 0; i < 4; ++i) {
                a = dot2(wr[i].x, xr[bb][i].x, a);
                a = dot2(wr[i].y, xr[bb][i].y, a);
                a = dot2(wr[i].z, xr[bb][i].z, a);
                a = dot2(wr[i].w, xr[bb][i].w, a);
            }
            a = ror_add<0x128>(a);
            a = ror_add<0x124>(a);
            a = ror_add<0x122>(a);
            a = ror_add<0x121>(a);      // full 16-lane (=full K) sum everywhere
            acc[bb] = a;
        }
        if (hp == 0) {
            const float bg = bgen[c];
            final4[q * 4 + cpart] = make_float4(acc[0] + bg, acc[1] + bg,
                                                acc[2] + bg, acc[3] + bg);
        }
    }
    __syncthreads();

    // stores: R5's proven pattern — thread (cq,bl,tt) stores float4 at
    // t = tt, tt+8, tt+16, tt+24 (256B-coalesced per wave per instr).
    {
        const int cq = tid & 7;
        const int bl = (tid >> 3) & 3;
        const int tt = tid >> 5;
        const float* ff = reinterpret_cast<const float*>(final4);
        float v[4];
        #pragma unroll
        for (int j = 0; j < 4; ++j) {
            const int cl = cq * 4 + j;
            // final4[cl] holds (b0..b0+3) for c=cblk+cl; pick bl
            v[j] = ff[cl * 4 + bl];
        }
        const float4 vv = make_float4(v[0], v[1], v[2], v[3]);
        float* o = out + (size_t)(b0 + bl) * Td * Cd + cblk + cq * 4;
        #pragma unroll
        for (int k = 0; k < 4; ++k) {
            const int t = tt + k * 8;
            *reinterpret_cast<float4*>(o + (size_t)t * Cd) = vv;
        }
    }
}

extern "C" void kernel_launch(void* const* d_in, const int* in_sizes, int n_in,
                              void* d_out, int out_size, void* d_ws, size_t ws_size,
                              hipStream_t stream) {
    const float* fmap = (const float*)d_in[0];   // [64,512,8,32]
    const float* Wgen = (const float*)d_in[9];   // [4096,512]
    const float* bgen = (const float*)d_in[10];  // [4096]
    float* out = (float*)d_out;                  // [64,32,4096]
    __half* ctx_h = (__half*)d_ws;                              // 64KB
    __half* W_h   = (__half*)((char*)d_ws + 65536);             // 4MB

    prep<<<dim3((Bd * Hd) / (4 * 8)), dim3(256), 0, stream>>>(fmap, Wgen, ctx_h, W_h);
    gemm_bcast<<<dim3(Cd / CG, Bd / 4), dim3(256), 0, stream>>>(ctx_h, W_h, bgen, out);
}